// Round 6
// baseline (1818.732 us; speedup 1.0000x reference)
//
#include <hip/hip_runtime.h>

#define TT 2048
#define BB 64
#define ROWS 4   // batch rows per lstm block (8 waves -> 2 waves/SIMD for TLP)

typedef float v2f __attribute__((ext_vector_type(2)));

__device__ __forceinline__ float frcp(float x) { return __builtin_amdgcn_rcpf(x); }
__device__ __forceinline__ float fsig(float x) { return frcp(1.f + __expf(-x)); }
__device__ __forceinline__ float ftan(float x) { return 1.f - 2.f * frcp(1.f + __expf(2.f * x)); }
__device__ __forceinline__ v2f fma2(v2f a, v2f b, v2f c) { return __builtin_elementwise_fma(a, b, c); }

// Raw barrier: LDS ordering only; global prefetch loads stay in flight
// (no vmcnt drain -- verified win in R5).
__device__ __forceinline__ void barrier_lgkm() {
  asm volatile("s_waitcnt lgkmcnt(0)\n\ts_barrier" ::: "memory");
}

// Canonical GCN wave64 sum-reduction via DPP (verified R4/R5):
// row_shr:1,2,4,8 then row_bcast:15, row_bcast:31; total lands in lane 63.
#define DPPADD(x, ctrl)                                                        \
  (x) += __builtin_bit_cast(float, __builtin_amdgcn_update_dpp(                \
             0, __builtin_bit_cast(int, (x)), (ctrl), 0xf, 0xf, true))

__device__ __forceinline__ float wave_sum64(float x) {
  DPPADD(x, 0x111);  // row_shr:1
  DPPADD(x, 0x112);  // row_shr:2
  DPPADD(x, 0x114);  // row_shr:4
  DPPADD(x, 0x118);  // row_shr:8
  DPPADD(x, 0x142);  // row_bcast:15
  DPPADD(x, 0x143);  // row_bcast:31
  return __builtin_bit_cast(
      float, __builtin_amdgcn_readlane(__builtin_bit_cast(int, x), 63));
}

// G[(b*Tc+tt)*256 + g] = sum_k X[...] * W_ih[g,k] + b_ih[g] + b_hh[g]
// Fused: blocks with blockIdx.y==0 also compute P[row] = x_row @ w21 + bias2
// from the staged As tiles (saves a separate full X re-read).
// Tiled fp32 GEMM: M = 64*Tc, N = 256, K = 256. grid=(Tc,4), block=256.
__global__ __launch_bounds__(256) void gates_gemm(const float* __restrict__ X,
                                                  const float* __restrict__ W,
                                                  const float* __restrict__ bih,
                                                  const float* __restrict__ bhh,
                                                  const float* __restrict__ w21,
                                                  const float* __restrict__ bias2,
                                                  float* __restrict__ G,
                                                  float* __restrict__ P,
                                                  int t0, int Tc) {
  __shared__ __align__(16) float As[32][64];  // As[k][m]
  __shared__ __align__(16) float Bs[32][64];  // Bs[k][n]
  __shared__ float w21_s[256];
  const int tid = threadIdx.x;
  const int m0 = blockIdx.x * 64;
  const int n0 = blockIdx.y * 64;
  const int bb = m0 / Tc;
  const int tt0 = m0 - bb * Tc;
  const int tx = tid & 15, ty = tid >> 4;
  const int r  = tid >> 2;
  const int kq = (tid & 3) * 8;
  const bool do_pz = (blockIdx.y == 0) && (tid < 64);
  w21_s[tid] = w21[tid];
  const float* xrow = X + ((size_t)(bb * TT + t0 + tt0 + r)) * 256 + kq;
  const float* wrow = W + (size_t)(n0 + r) * 257 + kq;
  float acc[4][4] = {};
  float psum = 0.f;
  for (int k0 = 0; k0 < 256; k0 += 32) {
    float4 a0 = *reinterpret_cast<const float4*>(xrow + k0);
    float4 a1 = *reinterpret_cast<const float4*>(xrow + k0 + 4);
    float bv[8];
#pragma unroll
    for (int u = 0; u < 8; ++u) bv[u] = wrow[k0 + u];
    if (k0 != 0) __syncthreads();
    As[kq+0][r]=a0.x; As[kq+1][r]=a0.y; As[kq+2][r]=a0.z; As[kq+3][r]=a0.w;
    As[kq+4][r]=a1.x; As[kq+5][r]=a1.y; As[kq+6][r]=a1.z; As[kq+7][r]=a1.w;
#pragma unroll
    for (int u = 0; u < 8; ++u) Bs[kq+u][r] = bv[u];
    __syncthreads();
#pragma unroll
    for (int kk = 0; kk < 32; ++kk) {
      float4 av = *reinterpret_cast<const float4*>(&As[kk][ty*4]);
      float4 bw = *reinterpret_cast<const float4*>(&Bs[kk][tx*4]);
      const float aa[4] = {av.x, av.y, av.z, av.w};
      const float bbv[4] = {bw.x, bw.y, bw.z, bw.w};
#pragma unroll
      for (int i = 0; i < 4; ++i)
#pragma unroll
        for (int j = 0; j < 4; ++j) acc[i][j] += aa[i] * bbv[j];
    }
    if (do_pz) {
#pragma unroll
      for (int kk = 0; kk < 32; ++kk) psum += As[kk][tid] * w21_s[k0 + kk];
    }
  }
  if (do_pz) P[m0 + tid] = psum + bias2[0];
  const int col = n0 + tx * 4;
  float bsum[4];
#pragma unroll
  for (int j = 0; j < 4; ++j) bsum[j] = bih[col + j] + bhh[col + j];
#pragma unroll
  for (int i = 0; i < 4; ++i) {
    float4 o;
    o.x = acc[i][0] + bsum[0];
    o.y = acc[i][1] + bsum[1];
    o.z = acc[i][2] + bsum[2];
    o.w = acc[i][3] + bsum[3];
    *reinterpret_cast<float4*>(&G[(size_t)(m0 + ty*4 + i) * 256 + col]) = o;
  }
}

// Serial recurrence: ROWS batch rows per block, 2 waves per row (R5 structure,
// verified). Wave w of a row owns units u = w*32 + (l&31); lanes 0-31 compute
// gates (i,g), lanes 32-63 gates (f,o); ig crosses halves via __shfl_xor(.,32);
// h crosses waves via ping-pong h_s; ONE raw barrier per step (shared by all
// ROWS rows -- gives each SIMD 2 waves to hide LDS/exp latencies).
__global__ __launch_bounds__(128 * ROWS, 1) void lstm_seq4(
    const float* __restrict__ G, const float* __restrict__ P,
    const float* __restrict__ Wih, const float* __restrict__ Whh,
    const float* __restrict__ w22, float* __restrict__ Z,
    float* __restrict__ hq, float* __restrict__ cq, int t0, int Tc) {
  const int tid = threadIdx.x;
  const int r   = tid >> 7;          // row slot within block
  const int rt  = tid & 127;
  const int b   = blockIdx.x * ROWS + r;
  const int w   = rt >> 6;           // wave within row: owns units w*32..+31
  const int l   = rt & 63;
  const int sub = l >> 5;            // 0: gates (i,g);  1: gates (f,o)
  const int u   = w * 32 + (l & 31); // owned hidden unit
  __shared__ __align__(16) float h_s[ROWS][2][64];

  // PyTorch gate-row order: i=0..63, f=64..127, g=128..191, o=192..255
  const int rowA = sub * 64 + u;     // i (sub0) or f (sub1)
  const int rowB = rowA + 128;       // g (sub0) or o (sub1)
  v2f whA[32], whB[32];
#pragma unroll
  for (int j = 0; j < 16; ++j) {
    float4 va = *reinterpret_cast<const float4*>(&Whh[(size_t)rowA * 64 + 4*j]);
    float4 vb = *reinterpret_cast<const float4*>(&Whh[(size_t)rowB * 64 + 4*j]);
    whA[2*j] = v2f{va.x, va.y}; whA[2*j+1] = v2f{va.z, va.w};
    whB[2*j] = v2f{vb.x, vb.y}; whB[2*j+1] = v2f{vb.z, vb.w};
  }
  const float wihLA = Wih[(size_t)rowA * 257 + 256];
  const float wihLB = Wih[(size_t)rowB * 257 + 256];
  const float w22r  = w22[l];
  // Branchless B-gate activation: sub0 tanh(x)=2*sig(2x)-1; sub1 sig(x).
  const float kB = sub ? 1.f : 2.f;
  const float mB = sub ? 1.f : 2.f;
  const float aB = sub ? 0.f : -1.f;

  float h = 0.f, c = 0.f;
  if (t0 != 0) { h = hq[b * 64 + u]; c = cq[b * 64 + u]; }
  if (l >= 32) h_s[r][0][u] = h;     // sub1 lanes of both waves cover u=0..63
  barrier_lgkm();

  const float* Gb = G + (size_t)b * Tc * 256;
  const float* Pb = P + (size_t)b * Tc;
  float* Zb = Z + (size_t)b * TT + t0;

  // Prefetch ring, distance 4 (static indices via full unroll).
  float grA[4], grB[4], pr[4];
#pragma unroll
  for (int q = 0; q < 4; ++q) {
    grA[q] = Gb[(size_t)q * 256 + rowA];
    grB[q] = Gb[(size_t)q * 256 + rowB];
    pr[q]  = Pb[q];
  }

  for (int tt = 0; tt < Tc; tt += 4) {
    float zs[4];
#pragma unroll
    for (int uu = 0; uu < 4; ++uu) {
      const int step = tt + uu;
      const int rb = uu & 1;                 // read-buffer parity (Tc%8==0)
      const float gxA = grA[uu], gxB = grB[uu], p0 = pr[uu];
      int pf = step + 4; if (pf > Tc - 1) pf = Tc - 1;
      grA[uu] = Gb[(size_t)pf * 256 + rowA];
      grB[uu] = Gb[(size_t)pf * 256 + rowB];
      pr[uu]  = Pb[pf];

      // pz raw sum: redundant per wave, bit-identical DPP sequence
      float rsum = h_s[r][rb][l] * w22r;
      const float tot = wave_sum64(rsum);
      const float pz = fsig(tot + p0);

      // two 64-wide dots against broadcast h(t-1); 8-deep fma chains
      v2f aA0{0.f,0.f}, aA1{0.f,0.f}, aA2{0.f,0.f}, aA3{0.f,0.f};
      v2f aB0{0.f,0.f}, aB1{0.f,0.f}, aB2{0.f,0.f}, aB3{0.f,0.f};
      const float4* hp = reinterpret_cast<const float4*>(h_s[r][rb]);
#pragma unroll
      for (int q = 0; q < 16; q += 2) {
        const float4 hv0 = hp[q];
        const float4 hv1 = hp[q+1];
        const v2f h01 = v2f{hv0.x, hv0.y}, h23 = v2f{hv0.z, hv0.w};
        const v2f h45 = v2f{hv1.x, hv1.y}, h67 = v2f{hv1.z, hv1.w};
        aA0 = fma2(h01, whA[2*q],   aA0);  aA1 = fma2(h23, whA[2*q+1], aA1);
        aA2 = fma2(h45, whA[2*q+2], aA2);  aA3 = fma2(h67, whA[2*q+3], aA3);
        aB0 = fma2(h01, whB[2*q],   aB0);  aB1 = fma2(h23, whB[2*q+1], aB1);
        aB2 = fma2(h45, whB[2*q+2], aB2);  aB3 = fma2(h67, whB[2*q+3], aB3);
      }
      const v2f sA = (aA0 + aA1) + (aA2 + aA3);
      const v2f sB = (aB0 + aB1) + (aB2 + aB3);
      const float preA = gxA + pz * wihLA + (sA.x + sA.y);
      const float preB = gxB + pz * wihLB + (sB.x + sB.y);
      const float actA = fsig(preA);                 // sig(i) / sig(f)
      const float actB = mB * fsig(kB * preB) + aB;  // tanh(g) / sig(o)

      const float prod = actA * actB;                // sub0: ig ; sub1: unused
      const float igx = __shfl_xor(prod, 32);        // sub1 lanes receive ig
      c = actA * c + igx;                            // meaningful on sub1
      h = actB * ftan(c);                            // meaningful on sub1
      if (l >= 32) h_s[r][rb ^ 1][u] = h;
      zs[uu] = pz;
      barrier_lgkm();
    }
    if (rt == 0) {
      float4 zo; zo.x = zs[0]; zo.y = zs[1]; zo.z = zs[2]; zo.w = zs[3];
      *reinterpret_cast<float4*>(&Zb[tt]) = zo;
    }
  }
  if (l >= 32) { hq[b * 64 + u] = h; cq[b * 64 + u] = c; }
}

// Fully-inline fp32 fallback (only if d_ws is too small for a 64-step chunk).
__global__ __launch_bounds__(256) void lstm_fallback(const float* __restrict__ X,
    const float* __restrict__ w21, const float* __restrict__ w22,
    const float* __restrict__ bias2, const float* __restrict__ Wih,
    const float* __restrict__ Whh, const float* __restrict__ bih,
    const float* __restrict__ bhh, float* __restrict__ Z) {
  const int b = blockIdx.x;
  const int g = threadIdx.x;
  const int lane = g & 63;
  __shared__ __align__(16) float h_s[64];
  __shared__ float act_s[256];
  __shared__ __align__(16) float x_s[256];
  __shared__ __align__(16) float w21_s[256];
  float wh[64];
#pragma unroll
  for (int j = 0; j < 64; j += 4) {
    float4 v = *reinterpret_cast<const float4*>(&Whh[(size_t)g*64 + j]);
    wh[j]=v.x; wh[j+1]=v.y; wh[j+2]=v.z; wh[j+3]=v.w;
  }
  const float wihL = Wih[(size_t)g*257 + 256];
  const float bias = bih[g] + bhh[g];
  const float b2 = bias2[0];
  const float w22r = w22[lane];
  w21_s[g] = w21[g];
  if (g < 64) h_s[g] = 0.f;
  float c = 0.f;
  __syncthreads();
  const float* Wr = Wih + (size_t)g * 257;
  for (int t = 0; t < TT; ++t) {
    x_s[g] = X[((size_t)b*TT + t)*256 + g];
    __syncthreads();
    float pv = h_s[lane] * w22r;
    {
      const float4 xq = *reinterpret_cast<const float4*>(&x_s[lane*4]);
      const float4 wq = *reinterpret_cast<const float4*>(&w21_s[lane*4]);
      pv += xq.x*wq.x + xq.y*wq.y + xq.z*wq.z + xq.w*wq.w;
    }
#pragma unroll
    for (int o = 32; o; o >>= 1) pv += __shfl_xor(pv, o);
    const float pz = fsig(pv + b2);
    float a0=0.f, a1=0.f, a2=0.f, a3=0.f;
#pragma unroll
    for (int j = 0; j < 64; j += 4) {
      float4 hv = *reinterpret_cast<const float4*>(&h_s[j]);
      a0 += hv.x*wh[j]; a1 += hv.y*wh[j+1]; a2 += hv.z*wh[j+2]; a3 += hv.w*wh[j+3];
    }
    float xd0=0.f, xd1=0.f, xd2=0.f, xd3=0.f;
    for (int k = 0; k < 256; k += 4) {
      const float4 xq = *reinterpret_cast<const float4*>(&x_s[k]);
      xd0 += xq.x*Wr[k]; xd1 += xq.y*Wr[k+1]; xd2 += xq.z*Wr[k+2]; xd3 += xq.w*Wr[k+3];
    }
    const float pre = bias + pz*wihL + ((a0+a1)+(a2+a3)) + ((xd0+xd1)+(xd2+xd3));
    act_s[g] = ((g >> 6) == 2) ? ftan(pre) : fsig(pre);
    if (g == 0) Z[(size_t)b*TT + t] = pz;
    __syncthreads();
    if (g < 64) {
      const float iv = act_s[g], fv = act_s[64+g], gv = act_s[128+g], ov = act_s[192+g];
      c = fv*c + iv*gv;
      h_s[g] = ov * ftan(c);
    }
    __syncthreads();
  }
}

extern "C" void kernel_launch(void* const* d_in, const int* in_sizes, int n_in,
                              void* d_out, int out_size, void* d_ws, size_t ws_size,
                              hipStream_t stream) {
  const float* X     = (const float*)d_in[0];  // [64,2048,256]
  const float* w21   = (const float*)d_in[1];  // [256]
  const float* w22   = (const float*)d_in[2];  // [64]
  const float* bias2 = (const float*)d_in[3];  // [1]
  const float* Wih   = (const float*)d_in[4];  // [256,257]
  const float* Whh   = (const float*)d_in[5];  // [256,64]
  const float* bih   = (const float*)d_in[6];  // [256]
  const float* bhh   = (const float*)d_in[7];  // [256]
  float* Z = (float*)d_out;                    // [64,2048]

  int Tc = 0;
  for (int cand = 2048; cand >= 64; cand >>= 1) {
    size_t need = (size_t)cand * (64*256*4 + 64*4) + 2*64*64*4;
    if (ws_size >= need) { Tc = cand; break; }
  }
  if (Tc == 0) {
    lstm_fallback<<<dim3(64), dim3(256), 0, stream>>>(X, w21, w22, bias2, Wih, Whh, bih, bhh, Z);
    return;
  }
  float* Gbuf = (float*)d_ws;                       // [64*Tc, 256]
  float* Pbuf = Gbuf + (size_t)64 * Tc * 256;       // [64*Tc]
  float* hq   = Pbuf + (size_t)64 * Tc;             // [64,64]
  float* cq   = hq + 64 * 64;                       // [64,64]
  for (int t0 = 0; t0 < 2048; t0 += Tc) {
    gates_gemm<<<dim3(Tc, 4), dim3(256), 0, stream>>>(X, Wih, bih, bhh, w21, bias2,
                                                      Gbuf, Pbuf, t0, Tc);
    lstm_seq4<<<dim3(BB / ROWS), dim3(128 * ROWS), 0, stream>>>(
        Gbuf, Pbuf, Wih, Whh, w22, Z, hq, cq, t0, Tc);
  }
}